// Round 5
// baseline (287.832 us; speedup 1.0000x reference)
//
#include <hip/hip_runtime.h>
#include <hip/hip_bf16.h>
#include <math.h>

// Problem constants
#define BQ 4
#define NQ 100
#define MQ 50
#define HWSZ 65536
#define NP 112   // padded N rows in partials (7 x 16)
#define MP 64    // padded M (4 x 16)
#define BK 64    // K depth (f32 elems) per LDS stage
#define LDA 72   // LDS row stride in bf16 elems (64 + 8 pad; 2-way banks = free)
#define DCLAMP 13.8155106f   // logit(1-1e-6) = -logit(1e-6)

typedef __attribute__((ext_vector_type(8))) short short8;
typedef __attribute__((ext_vector_type(4))) float f32x4;

// Barrier WITHOUT vmcnt(0) drain: our global loads target registers (wave-
// private), so cross-wave correctness only needs LDS ops drained. This keeps
// register prefetches in flight across the barrier (the compiler still emits
// per-use vmcnt(N) before consumption). __syncthreads() would drain vmcnt(0)
// and stall every wave on its own just-issued prefetch.
__device__ __forceinline__ void barrier_lds_only() {
    asm volatile("s_waitcnt lgkmcnt(0)\n\ts_barrier" ::: "memory");
}

// d = log(pm)-log(1-pm) = clamp(x, +-13.8155) EXACTLY (logit o clip o sigmoid).
// pm = sigmoid(clamp(x)); l1m = log(1-pm) = -log(1+e^xc).
__device__ __forceinline__ void xform2(float x, float& d, float& pm, float& l1m) {
    float xc = fminf(fmaxf(x, -DCLAMP), DCLAMP);
    d = xc;
    float e = __expf(xc);                       // in [1e-6, 1e6], no overflow
    float r = __builtin_amdgcn_rcpf(1.0f + e);
    pm = e * r;
    l1m = -__logf(1.0f + e);
}

// pack two floats -> two bf16 (RTNE) in one u32
__device__ __forceinline__ unsigned pk2(float a, float b) {
    __hip_bfloat162 h = __float22bfloat162_rn(float2{a, b});
    unsigned u;
    __builtin_memcpy(&u, &h, 4);
    return u;
}

// build a bf16x8 MFMA fragment from 8 consecutive floats (two float4)
__device__ __forceinline__ short8 mk8(float4 a, float4 b) {
    union { short8 s; unsigned u[4]; } r;
    r.u[0] = pk2(a.x, a.y); r.u[1] = pk2(a.z, a.w);
    r.u[2] = pk2(b.x, b.y); r.u[3] = pk2(b.z, b.w);
    return r.s;
}

// One block: K range [chunk*Kc, ...), N rows [ROW0, ROW0+16*NT).
// Single LDS-only barrier per K-step; A (d,pm) double-buffered through LDS;
// B fragments direct from global per wave (wave = m-tile). Depth-2 register
// prefetch: loads for step s+2 issued at step s. Rows beyond NQ/MQ are
// index-clamped -> finite garbage in partial rows/cols the epilogue never reads.
template <int NT, int ROW0, bool DO_TS>
__device__ __forceinline__ void run_block(
    const float* __restrict__ pred_masks, const float* __restrict__ tgt_masks,
    float* __restrict__ part1, float* __restrict__ part2,
    float* __restrict__ rspart, float* __restrict__ tspart,
    int nch, int Kc, int chunk, int b,
    unsigned short* ldsAd, unsigned short* ldsApm)   // each [2][64*LDA]
{
    const int t    = threadIdx.x;
    const int lane = t & 63;
    const int wv   = t >> 6;    // wave id = m-tile
    const int kq   = t & 15;    // 16B (4-float) chunk within BK (staging)
    const int rg   = t >> 4;    // row group 0..15 (staging)

    const long kbase0 = (long)chunk * Kc;
    const int nsteps = Kc / BK;   // >= 8

    f32x4 acc1[NT], acc2[NT];
    #pragma unroll
    for (int i = 0; i < NT; i++) { acc1[i] = (f32x4){0.f,0.f,0.f,0.f}; acc2[i] = (f32x4){0.f,0.f,0.f,0.f}; }
    float rsl[NT], rsp[NT];
    #pragma unroll
    for (int i = 0; i < NT; i++) { rsl[i] = 0.f; rsp[i] = 0.f; }
    float ts = 0.f;

    // A staging pointers (row-clamped; clamped rows produce garbage partials in
    // rows 100..111 which are never read)
    const float* ap[NT];
    #pragma unroll
    for (int i = 0; i < NT; i++) {
        const int arow = min(ROW0 + i * 16 + rg, NQ - 1);
        ap[i] = pred_masks + (((long)(b * NQ + arow)) << 16) + kbase0 + kq * 4;
    }
    // B fragment pointer (operand layout: col=lane&15, k=(lane>>4)*8+j)
    const int brow = min(wv * 16 + (lane & 15), MQ - 1);
    const float* bp = tgt_masks + (((long)(b * MQ + brow)) << 16) + kbase0 + (lane >> 4) * 8;

    float4 apf[2][NT], bpf[2][4];
    // prologue: issue steps 0 and 1
    #pragma unroll
    for (int pb = 0; pb < 2; ++pb) {
        #pragma unroll
        for (int i = 0; i < NT; i++) { apf[pb][i] = *(const float4*)ap[i]; ap[i] += BK; }
        bpf[pb][0] = *(const float4*)(bp +  0);
        bpf[pb][1] = *(const float4*)(bp +  4);
        bpf[pb][2] = *(const float4*)(bp + 32);
        bpf[pb][3] = *(const float4*)(bp + 36);
        bp += BK;
    }

    const int aoff = (lane & 15) * LDA;
    const int koff = (lane >> 4) * 8;

    for (int s = 0; s < nsteps; ++s) {
        const int buf = s & 1;
        unsigned short* lAd  = ldsAd  + buf * (64 * LDA);
        unsigned short* lApm = ldsApm + buf * (64 * LDA);

        // ---- B fragments for this step (registers only) ----
        const short8 bf0 = mk8(bpf[buf][0], bpf[buf][1]);
        const short8 bf1 = mk8(bpf[buf][2], bpf[buf][3]);
        if (DO_TS)
            ts += bpf[buf][0].x + bpf[buf][0].y + bpf[buf][0].z + bpf[buf][0].w
                + bpf[buf][1].x + bpf[buf][1].y + bpf[buf][1].z + bpf[buf][1].w
                + bpf[buf][2].x + bpf[buf][2].y + bpf[buf][2].z + bpf[buf][2].w
                + bpf[buf][3].x + bpf[buf][3].y + bpf[buf][3].z + bpf[buf][3].w;

        // ---- transform A regs -> LDS buf ----
        #pragma unroll
        for (int i = 0; i < NT; i++) {
            const float4 v = apf[buf][i];
            float d0,d1,d2,d3, p0,p1,p2,p3, l;
            xform2(v.x, d0, p0, l); rsl[i] += l; rsp[i] += p0;
            xform2(v.y, d1, p1, l); rsl[i] += l; rsp[i] += p1;
            xform2(v.z, d2, p2, l); rsl[i] += l; rsp[i] += p2;
            xform2(v.w, d3, p3, l); rsl[i] += l; rsp[i] += p3;
            const int row = i * 16 + rg;
            *(uint2*)&lAd[row * LDA + kq * 4]  = make_uint2(pk2(d0, d1), pk2(d2, d3));
            *(uint2*)&lApm[row * LDA + kq * 4] = make_uint2(pk2(p0, p1), pk2(p2, p3));
        }

        barrier_lds_only();   // LDS drained; global prefetches stay in flight

        // ---- issue loads for step s+2 into buf (full step of slack) ----
        if (s + 2 < nsteps) {
            #pragma unroll
            for (int i = 0; i < NT; i++) { apf[buf][i] = *(const float4*)ap[i]; ap[i] += BK; }
            bpf[buf][0] = *(const float4*)(bp +  0);
            bpf[buf][1] = *(const float4*)(bp +  4);
            bpf[buf][2] = *(const float4*)(bp + 32);
            bpf[buf][3] = *(const float4*)(bp + 36);
            bp += BK;
        }

        // ---- MFMA: wave wv = m-tile, NT n-tiles, both matrices ----
        #pragma unroll
        for (int ks = 0; ks < 2; ++ks) {
            const short8 bfr = ks ? bf1 : bf0;
            const int kk = ks * 32 + koff;
            #pragma unroll
            for (int nt = 0; nt < NT; ++nt) {
                const short8 a1 = *(const short8*)&lAd[(nt * 16) * LDA + aoff + kk];
                acc1[nt] = __builtin_amdgcn_mfma_f32_16x16x32_bf16(a1, bfr, acc1[nt], 0, 0, 0);
                const short8 a2 = *(const short8*)&lApm[(nt * 16) * LDA + aoff + kk];
                acc2[nt] = __builtin_amdgcn_mfma_f32_16x16x32_bf16(a2, bfr, acc2[nt], 0, 0, 0);
            }
        }
        // no second barrier: next step writes the other LDS buffer
    }

    // ---- store C partials: C/D layout col=lane&15, row=(lane>>4)*4+reg ----
    const long pbase = ((long)(b * nch + chunk)) * NP * MP;
    const int mloc = wv * 16 + (lane & 15);
    const int nr0 = (lane >> 4) * 4;
    #pragma unroll
    for (int nt = 0; nt < NT; ++nt) {
        #pragma unroll
        for (int r = 0; r < 4; ++r) {
            const int ng = ROW0 + nt * 16 + nr0 + r;
            part1[pbase + ng * MP + mloc] = acc1[nt][r];
            part2[pbase + ng * MP + mloc] = acc2[nt][r];
        }
    }

    // ---- ts column sums: lanes {m,m+16,m+32,m+48} hold column m's partials ----
    if (DO_TS) {
        ts += __shfl_xor(ts, 16);
        ts += __shfl_xor(ts, 32);
        if (lane < 16)
            tspart[(long)(b * nch + chunk) * MP + wv * 16 + lane] = ts;
    }

    // ---- row-sum reductions via LDS (full barrier is fine here, once) ----
    __syncthreads();
    float2* red = (float2*)ldsAd;   // [16*NT][16], fits in 2 buffers (18 KB)
    #pragma unroll
    for (int i = 0; i < NT; i++) red[(i * 16 + rg) * 16 + kq] = make_float2(rsl[i], rsp[i]);
    __syncthreads();

    if (t < 16 * NT) {
        float a = 0.f, c = 0.f;
        #pragma unroll
        for (int j = 0; j < 16; j++) { float2 v = red[t * 16 + j]; a += v.x; c += v.y; }
        const long rb = ((long)(b * nch + chunk) * NP + ROW0 + t) * 2;
        rspart[rb + 0] = a;
        rspart[rb + 1] = c;
    }
}

__global__ __launch_bounds__(256, 2)
void matcher_main(const float* __restrict__ pred_masks,  // [4][100][65536]
                  const float* __restrict__ tgt_masks,   // [4][50][65536]
                  float* __restrict__ part1,             // [4][nch][112][64]
                  float* __restrict__ part2,             // [4][nch][112][64]
                  float* __restrict__ rspart,            // [4][nch][112][2]
                  float* __restrict__ tspart,            // [4][nch][64]
                  int nch, int Kc)
{
    __shared__ __align__(16) unsigned short ldsAd[2 * 64 * LDA];
    __shared__ __align__(16) unsigned short ldsApm[2 * 64 * LDA];

    const int chunk = blockIdx.x;
    const int b     = blockIdx.y;
    if (blockIdx.z == 0)
        run_block<4, 0, true>(pred_masks, tgt_masks, part1, part2, rspart, tspart,
                              nch, Kc, chunk, b, ldsAd, ldsApm);
    else
        run_block<3, 64, false>(pred_masks, tgt_masks, part1, part2, rspart, tspart,
                                nch, Kc, chunk, b, ldsAd, ldsApm);
}

// Epilogue: one block per (b,n), 1024 threads; 16-way chunk-group reduction.
__global__ __launch_bounds__(1024)
void matcher_epilogue(const float* __restrict__ pred_logits, // [4][100][2]
                      const float* __restrict__ pred_style,  // [4][100][4]
                      const int*   __restrict__ styles,      // [4][50]
                      const float* __restrict__ part1,
                      const float* __restrict__ part2,
                      const float* __restrict__ rspart,
                      const float* __restrict__ tspart,
                      float* __restrict__ out, int nch)
{
    __shared__ float red1[16][64], red2[16][64], redt[16][64];
    __shared__ float slw[16], spw[16];

    const int blk = blockIdx.x;          // 0..399
    const int b = blk / NQ, n = blk % NQ;
    const int t = threadIdx.x;
    const int m = t & 63, cg = t >> 6;   // cg in 0..15

    float S1 = 0.f, S2 = 0.f, St = 0.f;
    for (int c = cg; c < nch; c += 16) {
        const long base = ((long)(b * nch + c) * NP + n) * MP + m;
        S1 += part1[base];
        S2 += part2[base];
        St += tspart[(long)(b * nch + c) * MP + m];
    }
    red1[cg][m] = S1; red2[cg][m] = S2; redt[cg][m] = St;

    // Sl/Sp across chunks: threads 0..nch-1 load, per-wave shuffle reduce
    float sl = 0.f, sp = 0.f;
    if (t < nch) {
        const float2 v = *(const float2*)&rspart[((long)(b * nch + t) * NP + n) * 2];
        sl = v.x; sp = v.y;
    }
    #pragma unroll
    for (int off = 32; off; off >>= 1) { sl += __shfl_down(sl, off); sp += __shfl_down(sp, off); }
    if ((t & 63) == 0) { slw[t >> 6] = sl; spw[t >> 6] = sp; }
    __syncthreads();

    if (t < MQ) {
        float Sl = 0.f, Sp = 0.f, s1 = 0.f, s2 = 0.f, st = 0.f;
        #pragma unroll
        for (int w = 0; w < 16; w++) {
            Sl += slw[w]; Sp += spw[w];
            s1 += red1[w][t]; s2 += red2[w][t]; st += redt[w][t];
        }

        // classification: -softmax(logits)[1]
        const float l0 = pred_logits[(b * NQ + n) * 2 + 0];
        const float l1 = pred_logits[(b * NQ + n) * 2 + 1];
        const float p1 = 1.0f / (1.0f + __expf(l0 - l1));

        // style: -softmax(style)[sid]
        const float* stp = &pred_style[(b * NQ + n) * 4];
        const float v0 = stp[0], v1 = stp[1], v2 = stp[2], v3 = stp[3];
        const float mx = fmaxf(fmaxf(v0, v1), fmaxf(v2, v3));
        const float e0 = __expf(v0 - mx), e1 = __expf(v1 - mx),
                    e2 = __expf(v2 - mx), e3 = __expf(v3 - mx);
        const float esum = e0 + e1 + e2 + e3;
        int sid = styles[b * MQ + t];
        sid = min(max(sid, 0), 3);
        const float ps = (sid == 0 ? e0 : sid == 1 ? e1 : sid == 2 ? e2 : e3) / esum;

        const float cost_mask = -(s1 + Sl) * (1.0f / (float)HWSZ);
        const float dice = 1.0f - (2.0f * s2 + 1.0f) / (Sp + st + 1.0f);

        float c = 2.0f * (-p1) + 5.0f * cost_mask + 5.0f * dice + 1.0f * (-ps);
        if (isnan(c)) c = 10000.0f;
        else if (isinf(c)) c = (c > 0.f) ? 10000.0f : -10000.0f;
        out[(b * NQ + n) * MQ + t] = c;
    }
}

extern "C" void kernel_launch(void* const* d_in, const int* in_sizes, int n_in,
                              void* d_out, int out_size, void* d_ws, size_t ws_size,
                              hipStream_t stream) {
    const float* pred_logits = (const float*)d_in[0];
    const float* pred_masks  = (const float*)d_in[1];
    const float* pred_style  = (const float*)d_in[2];
    const float* tgt_masks   = (const float*)d_in[3];
    const int*   styles      = (const int*)d_in[4];
    float* out = (float*)d_out;

    // ws layout: part1/part2 [4][nch][112][64], rspart [4][nch][112][2], tspart [4][nch][64]
    int nch = 8;
    for (int cand = 128; cand >= 8; cand >>= 1) {
        size_t need = (size_t)cand * (2ull * BQ * NP * MP * 4ull
                                      + (size_t)BQ * NP * 2 * 4ull
                                      + (size_t)BQ * MP * 4ull);
        if (need <= ws_size) { nch = cand; break; }
    }
    const int Kc = HWSZ / nch;

    float* part1  = (float*)d_ws;
    float* part2  = part1 + (size_t)BQ * nch * NP * MP;
    float* rspart = part2 + (size_t)BQ * nch * NP * MP;
    float* tspart = rspart + (size_t)BQ * nch * NP * 2;

    dim3 grid(nch, BQ, 2);
    matcher_main<<<grid, 256, 0, stream>>>(pred_masks, tgt_masks, part1, part2, rspart, tspart, nch, Kc);

    matcher_epilogue<<<BQ * NQ, 1024, 0, stream>>>(
        pred_logits, pred_style, styles, part1, part2, rspart, tspart, out, nch);
}

// Round 6
// 216.188 us; speedup vs baseline: 1.3314x; 1.3314x over previous
//
#include <hip/hip_runtime.h>
#include <hip/hip_bf16.h>
#include <math.h>

// Problem constants
#define BQ 4
#define NQ 100
#define MQ 50
#define HWSZ 65536
#define NP 112   // padded N rows in partials (7 x 16)
#define MP 64    // padded M (4 x 16)
#define BK 64    // K depth (f32 elems) per LDS stage
#define LDA 72   // LDS row stride in bf16 elems (64 + 8 pad; 2-way banks = free)
#define DCLAMP 13.8155106f   // logit(1-1e-6) = -logit(1e-6)

typedef __attribute__((ext_vector_type(8))) short short8;
typedef __attribute__((ext_vector_type(4))) float f32x4;

// Barrier WITHOUT vmcnt(0) drain: our global loads target registers (wave-
// private), so cross-wave correctness only needs LDS ops drained. Keeps
// register prefetches in flight across the barrier (compiler still emits
// per-use vmcnt(N) before consumption). __syncthreads() would drain vmcnt(0).
__device__ __forceinline__ void barrier_lds_only() {
    asm volatile("s_waitcnt lgkmcnt(0)\n\ts_barrier" ::: "memory");
}

// d = log(pm)-log(1-pm) = clamp(x, +-13.8155) EXACTLY (logit o clip o sigmoid).
// pm = sigmoid(clamp(x)); l1m = log(1-pm) = -log(1+e^xc).
__device__ __forceinline__ void xform2(float x, float& d, float& pm, float& l1m) {
    float xc = fminf(fmaxf(x, -DCLAMP), DCLAMP);
    d = xc;
    float e = __expf(xc);                       // in [1e-6, 1e6], no overflow
    float r = __builtin_amdgcn_rcpf(1.0f + e);
    pm = e * r;
    l1m = -__logf(1.0f + e);
}

// pack two floats -> two bf16 (RTNE) in one u32
__device__ __forceinline__ unsigned pk2(float a, float b) {
    __hip_bfloat162 h = __float22bfloat162_rn(float2{a, b});
    unsigned u;
    __builtin_memcpy(&u, &h, 4);
    return u;
}

// build a bf16x8 MFMA fragment from 8 consecutive floats (two float4)
__device__ __forceinline__ short8 mk8(float4 a, float4 b) {
    union { short8 s; unsigned u[4]; } r;
    r.u[0] = pk2(a.x, a.y); r.u[1] = pk2(a.z, a.w);
    r.u[2] = pk2(b.x, b.y); r.u[3] = pk2(b.z, b.w);
    return r.s;
}

// One pipeline step at a FIXED parity: consumes apf/bpf (named register sets,
// all indices compile-time constant -> no scratch demotion), writes LDS buf,
// LDS-only barrier, optionally issues prefetch for step s+2 into the SAME
// (now dead) register set, then runs the MFMA block reading LDS buf.
template <int NT, bool DO_TS>
__device__ __forceinline__ void pipe_step(
    float4 (&apf)[NT], float4 (&bpf)[4],
    const float* (&ap)[NT], const float*& bp,
    unsigned short* lAd, unsigned short* lApm,
    bool do_prefetch,
    f32x4 (&acc1)[NT], f32x4 (&acc2)[NT],
    float (&rsl)[NT], float (&rsp)[NT], float& ts,
    int aoff, int koff, int rg, int kq)
{
    // ---- B fragments for this step (registers only) ----
    const short8 bf0 = mk8(bpf[0], bpf[1]);
    const short8 bf1 = mk8(bpf[2], bpf[3]);
    if (DO_TS)
        ts += bpf[0].x + bpf[0].y + bpf[0].z + bpf[0].w
            + bpf[1].x + bpf[1].y + bpf[1].z + bpf[1].w
            + bpf[2].x + bpf[2].y + bpf[2].z + bpf[2].w
            + bpf[3].x + bpf[3].y + bpf[3].z + bpf[3].w;

    // ---- transform A regs -> LDS buf ----
    #pragma unroll
    for (int i = 0; i < NT; i++) {
        const float4 v = apf[i];
        float d0,d1,d2,d3, p0,p1,p2,p3, l;
        xform2(v.x, d0, p0, l); rsl[i] += l; rsp[i] += p0;
        xform2(v.y, d1, p1, l); rsl[i] += l; rsp[i] += p1;
        xform2(v.z, d2, p2, l); rsl[i] += l; rsp[i] += p2;
        xform2(v.w, d3, p3, l); rsl[i] += l; rsp[i] += p3;
        const int row = i * 16 + rg;
        *(uint2*)&lAd[row * LDA + kq * 4]  = make_uint2(pk2(d0, d1), pk2(d2, d3));
        *(uint2*)&lApm[row * LDA + kq * 4] = make_uint2(pk2(p0, p1), pk2(p2, p3));
    }

    barrier_lds_only();   // LDS drained; global prefetches stay in flight

    // ---- issue loads for step s+2 (regs are dead now; full step of slack) ----
    if (do_prefetch) {
        #pragma unroll
        for (int i = 0; i < NT; i++) { apf[i] = *(const float4*)ap[i]; ap[i] += BK; }
        bpf[0] = *(const float4*)(bp +  0);
        bpf[1] = *(const float4*)(bp +  4);
        bpf[2] = *(const float4*)(bp + 32);
        bpf[3] = *(const float4*)(bp + 36);
        bp += BK;
    }

    // ---- MFMA: this wave's m-tile vs NT n-tiles, both matrices ----
    #pragma unroll
    for (int ks = 0; ks < 2; ++ks) {
        const short8 bfr = ks ? bf1 : bf0;
        const int kk = ks * 32 + koff;
        #pragma unroll
        for (int nt = 0; nt < NT; ++nt) {
            const short8 a1 = *(const short8*)&lAd[(nt * 16) * LDA + aoff + kk];
            acc1[nt] = __builtin_amdgcn_mfma_f32_16x16x32_bf16(a1, bfr, acc1[nt], 0, 0, 0);
            const short8 a2 = *(const short8*)&lApm[(nt * 16) * LDA + aoff + kk];
            acc2[nt] = __builtin_amdgcn_mfma_f32_16x16x32_bf16(a2, bfr, acc2[nt], 0, 0, 0);
        }
    }
    // no trailing barrier: the next step writes the OTHER LDS buffer
}

// One block: K range [chunk*Kc, ...), N rows [ROW0, ROW0+16*NT).
template <int NT, int ROW0, bool DO_TS>
__device__ __forceinline__ void run_block(
    const float* __restrict__ pred_masks, const float* __restrict__ tgt_masks,
    float* __restrict__ part1, float* __restrict__ part2,
    float* __restrict__ rspart, float* __restrict__ tspart,
    int nch, int Kc, int chunk, int b,
    unsigned short* ldsAd, unsigned short* ldsApm)   // each [2][64*LDA]
{
    const int t    = threadIdx.x;
    const int lane = t & 63;
    const int wv   = t >> 6;    // wave id = m-tile
    const int kq   = t & 15;    // 16B (4-float) chunk within BK (staging)
    const int rg   = t >> 4;    // row group 0..15 (staging)

    const long kbase0 = (long)chunk * Kc;
    const int nsteps = Kc / BK;   // = 1024/nch, always even

    f32x4 acc1[NT], acc2[NT];
    #pragma unroll
    for (int i = 0; i < NT; i++) { acc1[i] = (f32x4){0.f,0.f,0.f,0.f}; acc2[i] = (f32x4){0.f,0.f,0.f,0.f}; }
    float rsl[NT], rsp[NT];
    #pragma unroll
    for (int i = 0; i < NT; i++) { rsl[i] = 0.f; rsp[i] = 0.f; }
    float ts = 0.f;

    // A staging pointers (row-clamped; clamped rows produce garbage partials
    // in rows 100..111 which are never read)
    const float* ap[NT];
    #pragma unroll
    for (int i = 0; i < NT; i++) {
        const int arow = min(ROW0 + i * 16 + rg, NQ - 1);
        ap[i] = pred_masks + (((long)(b * NQ + arow)) << 16) + kbase0 + kq * 4;
    }
    // B fragment pointer (operand layout: col=lane&15, k=(lane>>4)*8+j)
    const int brow = min(wv * 16 + (lane & 15), MQ - 1);
    const float* bp = tgt_masks + (((long)(b * MQ + brow)) << 16) + kbase0 + (lane >> 4) * 8;

    // Two NAMED prefetch register sets (even / odd steps) — constant indices only.
    float4 apf0[NT], bpf0[4], apf1[NT], bpf1[4];
    #pragma unroll
    for (int i = 0; i < NT; i++) { apf0[i] = *(const float4*)ap[i]; ap[i] += BK; }
    bpf0[0] = *(const float4*)(bp +  0);
    bpf0[1] = *(const float4*)(bp +  4);
    bpf0[2] = *(const float4*)(bp + 32);
    bpf0[3] = *(const float4*)(bp + 36);
    bp += BK;
    #pragma unroll
    for (int i = 0; i < NT; i++) { apf1[i] = *(const float4*)ap[i]; ap[i] += BK; }
    bpf1[0] = *(const float4*)(bp +  0);
    bpf1[1] = *(const float4*)(bp +  4);
    bpf1[2] = *(const float4*)(bp + 32);
    bpf1[3] = *(const float4*)(bp + 36);
    bp += BK;

    const int aoff = (lane & 15) * LDA;
    const int koff = (lane >> 4) * 8;

    unsigned short* lAd0  = ldsAd;
    unsigned short* lApm0 = ldsApm;
    unsigned short* lAd1  = ldsAd  + 64 * LDA;
    unsigned short* lApm1 = ldsApm + 64 * LDA;

    for (int s = 0; s < nsteps; s += 2) {
        pipe_step<NT, DO_TS>(apf0, bpf0, ap, bp, lAd0, lApm0, s + 2 < nsteps,
                             acc1, acc2, rsl, rsp, ts, aoff, koff, rg, kq);
        pipe_step<NT, DO_TS>(apf1, bpf1, ap, bp, lAd1, lApm1, s + 3 < nsteps,
                             acc1, acc2, rsl, rsp, ts, aoff, koff, rg, kq);
    }

    // ---- store C partials: C/D layout col=lane&15, row=(lane>>4)*4+reg ----
    const long pbase = ((long)(b * nch + chunk)) * NP * MP;
    const int mloc = wv * 16 + (lane & 15);
    const int nr0 = (lane >> 4) * 4;
    #pragma unroll
    for (int nt = 0; nt < NT; ++nt) {
        #pragma unroll
        for (int r = 0; r < 4; ++r) {
            const int ng = ROW0 + nt * 16 + nr0 + r;
            part1[pbase + ng * MP + mloc] = acc1[nt][r];
            part2[pbase + ng * MP + mloc] = acc2[nt][r];
        }
    }

    // ---- ts column sums: lanes {m,m+16,m+32,m+48} hold column m's partials ----
    if (DO_TS) {
        ts += __shfl_xor(ts, 16);
        ts += __shfl_xor(ts, 32);
        if (lane < 16)
            tspart[(long)(b * nch + chunk) * MP + wv * 16 + lane] = ts;
    }

    // ---- row-sum reductions via LDS ----
    __syncthreads();
    float2* red = (float2*)ldsAd;   // [16*NT][16], fits in the 2 buffers (18 KB)
    #pragma unroll
    for (int i = 0; i < NT; i++) red[(i * 16 + rg) * 16 + kq] = make_float2(rsl[i], rsp[i]);
    __syncthreads();

    if (t < 16 * NT) {
        float a = 0.f, c = 0.f;
        #pragma unroll
        for (int j = 0; j < 16; j++) { float2 v = red[t * 16 + j]; a += v.x; c += v.y; }
        const long rb = ((long)(b * nch + chunk) * NP + ROW0 + t) * 2;
        rspart[rb + 0] = a;
        rspart[rb + 1] = c;
    }
}

__global__ __launch_bounds__(256, 2)
void matcher_main(const float* __restrict__ pred_masks,  // [4][100][65536]
                  const float* __restrict__ tgt_masks,   // [4][50][65536]
                  float* __restrict__ part1,             // [4][nch][112][64]
                  float* __restrict__ part2,             // [4][nch][112][64]
                  float* __restrict__ rspart,            // [4][nch][112][2]
                  float* __restrict__ tspart,            // [4][nch][64]
                  int nch, int Kc)
{
    __shared__ __align__(16) unsigned short ldsAd[2 * 64 * LDA];
    __shared__ __align__(16) unsigned short ldsApm[2 * 64 * LDA];

    const int chunk = blockIdx.x;
    const int b     = blockIdx.y;
    if (blockIdx.z == 0)
        run_block<4, 0, true>(pred_masks, tgt_masks, part1, part2, rspart, tspart,
                              nch, Kc, chunk, b, ldsAd, ldsApm);
    else
        run_block<3, 64, false>(pred_masks, tgt_masks, part1, part2, rspart, tspart,
                                nch, Kc, chunk, b, ldsAd, ldsApm);
}

// Epilogue: one block per (b,n), 1024 threads; 16-way chunk-group reduction.
__global__ __launch_bounds__(1024)
void matcher_epilogue(const float* __restrict__ pred_logits, // [4][100][2]
                      const float* __restrict__ pred_style,  // [4][100][4]
                      const int*   __restrict__ styles,      // [4][50]
                      const float* __restrict__ part1,
                      const float* __restrict__ part2,
                      const float* __restrict__ rspart,
                      const float* __restrict__ tspart,
                      float* __restrict__ out, int nch)
{
    __shared__ float red1[16][64], red2[16][64], redt[16][64];
    __shared__ float slw[16], spw[16];

    const int blk = blockIdx.x;          // 0..399
    const int b = blk / NQ, n = blk % NQ;
    const int t = threadIdx.x;
    const int m = t & 63, cg = t >> 6;   // cg in 0..15

    float S1 = 0.f, S2 = 0.f, St = 0.f;
    for (int c = cg; c < nch; c += 16) {
        const long base = ((long)(b * nch + c) * NP + n) * MP + m;
        S1 += part1[base];
        S2 += part2[base];
        St += tspart[(long)(b * nch + c) * MP + m];
    }
    red1[cg][m] = S1; red2[cg][m] = S2; redt[cg][m] = St;

    // Sl/Sp across chunks: threads 0..nch-1 load, per-wave shuffle reduce
    float sl = 0.f, sp = 0.f;
    if (t < nch) {
        const float2 v = *(const float2*)&rspart[((long)(b * nch + t) * NP + n) * 2];
        sl = v.x; sp = v.y;
    }
    #pragma unroll
    for (int off = 32; off; off >>= 1) { sl += __shfl_down(sl, off); sp += __shfl_down(sp, off); }
    if ((t & 63) == 0) { slw[t >> 6] = sl; spw[t >> 6] = sp; }
    __syncthreads();

    if (t < MQ) {
        float Sl = 0.f, Sp = 0.f, s1 = 0.f, s2 = 0.f, st = 0.f;
        #pragma unroll
        for (int w = 0; w < 16; w++) {
            Sl += slw[w]; Sp += spw[w];
            s1 += red1[w][t]; s2 += red2[w][t]; st += redt[w][t];
        }

        // classification: -softmax(logits)[1]
        const float l0 = pred_logits[(b * NQ + n) * 2 + 0];
        const float l1 = pred_logits[(b * NQ + n) * 2 + 1];
        const float p1 = 1.0f / (1.0f + __expf(l0 - l1));

        // style: -softmax(style)[sid]
        const float* stp = &pred_style[(b * NQ + n) * 4];
        const float v0 = stp[0], v1 = stp[1], v2 = stp[2], v3 = stp[3];
        const float mx = fmaxf(fmaxf(v0, v1), fmaxf(v2, v3));
        const float e0 = __expf(v0 - mx), e1 = __expf(v1 - mx),
                    e2 = __expf(v2 - mx), e3 = __expf(v3 - mx);
        const float esum = e0 + e1 + e2 + e3;
        int sid = styles[b * MQ + t];
        sid = min(max(sid, 0), 3);
        const float ps = (sid == 0 ? e0 : sid == 1 ? e1 : sid == 2 ? e2 : e3) / esum;

        const float cost_mask = -(s1 + Sl) * (1.0f / (float)HWSZ);
        const float dice = 1.0f - (2.0f * s2 + 1.0f) / (Sp + st + 1.0f);

        float c = 2.0f * (-p1) + 5.0f * cost_mask + 5.0f * dice + 1.0f * (-ps);
        if (isnan(c)) c = 10000.0f;
        else if (isinf(c)) c = (c > 0.f) ? 10000.0f : -10000.0f;
        out[(b * NQ + n) * MQ + t] = c;
    }
}

extern "C" void kernel_launch(void* const* d_in, const int* in_sizes, int n_in,
                              void* d_out, int out_size, void* d_ws, size_t ws_size,
                              hipStream_t stream) {
    const float* pred_logits = (const float*)d_in[0];
    const float* pred_masks  = (const float*)d_in[1];
    const float* pred_style  = (const float*)d_in[2];
    const float* tgt_masks   = (const float*)d_in[3];
    const int*   styles      = (const int*)d_in[4];
    float* out = (float*)d_out;

    // ws layout: part1/part2 [4][nch][112][64], rspart [4][nch][112][2], tspart [4][nch][64]
    int nch = 8;
    for (int cand = 128; cand >= 8; cand >>= 1) {
        size_t need = (size_t)cand * (2ull * BQ * NP * MP * 4ull
                                      + (size_t)BQ * NP * 2 * 4ull
                                      + (size_t)BQ * MP * 4ull);
        if (need <= ws_size) { nch = cand; break; }
    }
    const int Kc = HWSZ / nch;

    float* part1  = (float*)d_ws;
    float* part2  = part1 + (size_t)BQ * nch * NP * MP;
    float* rspart = part2 + (size_t)BQ * nch * NP * MP;
    float* tspart = rspart + (size_t)BQ * nch * NP * 2;

    dim3 grid(nch, BQ, 2);
    matcher_main<<<grid, 256, 0, stream>>>(pred_masks, tgt_masks, part1, part2, rspart, tspart, nch, Kc);

    matcher_epilogue<<<BQ * NQ, 1024, 0, stream>>>(
        pred_logits, pred_style, styles, part1, part2, rspart, tspart, out, nch);
}